// Round 1
// 429.615 us; speedup vs baseline: 1.0401x; 1.0401x over previous
//
#include <hip/hip_runtime.h>
#include <math.h>

#define B  32
#define A  512
#define EH 256
#define DH 384
#define HW 4096   // 64*64
#define NCHUNK 8          // a-axis split for k2
#define ACH (A / NCHUNK)  // 64 a-values per chunk
#define P4 (HW / 4)       // 1024 float4 pixels per batch

typedef float f4 __attribute__((ext_vector_type(4)));   // native vector for nontemporal builtins

// ---------------------------------------------------------------------------
// k2 (fused k1+k2):
//   phase 1: block computes dec_proj for its 64 a-values (W_dec chunk is
//            L2-resident: 768 KB total, re-read 4x per batch -> ~2 us chipwide)
//   phase 2: partial[b][chunk][p] = sum_{a in chunk} w_energy[a]*tanh(weo+dp)
//   weo is read exactly once -> nontemporal loads keep it out of L2's way.
//   tanh(v) = 1 - 2/(exp2(2*log2e*v)+1) -> v_exp_f32 + v_rcp_f32
// ---------------------------------------------------------------------------
__global__ void k_scores_part(const float* __restrict__ weo,
                              const float* __restrict__ dec_h,
                              const float* __restrict__ W_dec,
                              const float* __restrict__ b_dec,
                              const float* __restrict__ w_energy,
                              float* __restrict__ partial) {
    __shared__ float s_dp[ACH];   // dec_proj * 2log2e (pre-scaled for exp2 arg)
    __shared__ float s_we[ACH];
    const int b  = blockIdx.z;
    const int a0 = blockIdx.y * ACH;
    const int p4 = blockIdx.x * blockDim.x + threadIdx.x;   // [0, 1024)
    const float C = 2.8853900817779268f;                    // 2*log2(e)

    // ---- phase 1: dec_proj for a0 .. a0+63, 16 a's per wave, 2-way ILP ----
    const int wave = threadIdx.x >> 6;
    const int lane = threadIdx.x & 63;
    const float* dh = dec_h + b * DH;
    #pragma unroll
    for (int i = 0; i < 16; i += 2) {
        const int a1 = wave * 16 + i;
        const int a2 = a1 + 1;
        const float* wd1 = W_dec + (size_t)(a0 + a1) * DH;
        const float* wd2 = W_dec + (size_t)(a0 + a2) * DH;
        float acc1 = 0.f, acc2 = 0.f;
        #pragma unroll
        for (int k = 0; k < DH; k += 64) {
            float d = dh[k + lane];
            acc1 = fmaf(d, wd1[k + lane], acc1);
            acc2 = fmaf(d, wd2[k + lane], acc2);
        }
        #pragma unroll
        for (int s = 32; s > 0; s >>= 1) {
            acc1 += __shfl_down(acc1, s);
            acc2 += __shfl_down(acc2, s);
        }
        if (lane == 0) {
            s_dp[a1] = (acc1 + b_dec[a0 + a1]) * C;
            s_dp[a2] = (acc2 + b_dec[a0 + a2]) * C;
        }
    }
    if (threadIdx.x < ACH) s_we[threadIdx.x] = w_energy[a0 + threadIdx.x];
    __syncthreads();

    // ---- phase 2: streaming tanh + channel contraction ----
    const f4* w4 = (const f4*)(weo + ((size_t)b * A + a0) * HW);
    f4 acc = (f4)(0.f);
    #pragma unroll 8
    for (int a = 0; a < ACH; ++a) {
        f4 x = __builtin_nontemporal_load(&w4[(size_t)a * P4 + p4]);
        float dp = s_dp[a];
        float we = s_we[a];
        float rx = __builtin_amdgcn_rcpf(__builtin_amdgcn_exp2f(fmaf(x.x, C, dp)) + 1.f);
        float ry = __builtin_amdgcn_rcpf(__builtin_amdgcn_exp2f(fmaf(x.y, C, dp)) + 1.f);
        float rz = __builtin_amdgcn_rcpf(__builtin_amdgcn_exp2f(fmaf(x.z, C, dp)) + 1.f);
        float rw = __builtin_amdgcn_rcpf(__builtin_amdgcn_exp2f(fmaf(x.w, C, dp)) + 1.f);
        acc.x = fmaf(we, fmaf(-2.f, rx, 1.f), acc.x);
        acc.y = fmaf(we, fmaf(-2.f, ry, 1.f), acc.y);
        acc.z = fmaf(we, fmaf(-2.f, rz, 1.f), acc.z);
        acc.w = fmaf(we, fmaf(-2.f, rw, 1.f), acc.w);
    }
    f4* out4 = (f4*)partial;
    __builtin_nontemporal_store(acc, &out4[((size_t)(b * NCHUNK + blockIdx.y)) * P4 + p4]);
}

// ---------------------------------------------------------------------------
// k3: scores[b][p] = sum_chunk partial[b][chunk][p] + b_energy; softmax -> alphas
// one block per batch; float4 throughout; partials are L2/L3-resident (4 MB)
// ---------------------------------------------------------------------------
__global__ void k_softmax(const float* __restrict__ partial,
                          const float* __restrict__ b_energy,
                          float* __restrict__ alphas) {
    __shared__ float red[256];
    const int b = blockIdx.x;
    const float be = b_energy[0];
    const float4* p4 = (const float4*)partial + (size_t)b * NCHUNK * P4;
    float4 v[4];
    float m = -INFINITY;
    #pragma unroll
    for (int i = 0; i < 4; ++i) {
        const int idx = threadIdx.x + i * 256;
        float4 s = make_float4(be, be, be, be);
        #pragma unroll
        for (int c = 0; c < NCHUNK; ++c) {
            float4 t = p4[(size_t)c * P4 + idx];
            s.x += t.x; s.y += t.y; s.z += t.z; s.w += t.w;
        }
        v[i] = s;
        m = fmaxf(m, fmaxf(fmaxf(s.x, s.y), fmaxf(s.z, s.w)));
    }
    red[threadIdx.x] = m; __syncthreads();
    for (int s2 = 128; s2 > 0; s2 >>= 1) {
        if (threadIdx.x < s2)
            red[threadIdx.x] = fmaxf(red[threadIdx.x], red[threadIdx.x + s2]);
        __syncthreads();
    }
    m = red[0]; __syncthreads();
    float sum = 0.f;
    #pragma unroll
    for (int i = 0; i < 4; ++i) {
        v[i].x = __expf(v[i].x - m); v[i].y = __expf(v[i].y - m);
        v[i].z = __expf(v[i].z - m); v[i].w = __expf(v[i].w - m);
        sum += v[i].x + v[i].y + v[i].z + v[i].w;
    }
    red[threadIdx.x] = sum; __syncthreads();
    for (int s2 = 128; s2 > 0; s2 >>= 1) {
        if (threadIdx.x < s2)
            red[threadIdx.x] += red[threadIdx.x + s2];
        __syncthreads();
    }
    const float inv = 1.f / red[0];
    float4* out = (float4*)(alphas + (size_t)b * HW);
    #pragma unroll
    for (int i = 0; i < 4; ++i)
        out[threadIdx.x + i * 256] =
            make_float4(v[i].x * inv, v[i].y * inv, v[i].z * inv, v[i].w * inv);
}

// ---------------------------------------------------------------------------
// k4: context[b][c] = sum_p enc[b][c][p] * alphas[b][p]
// one wave per (b,c); alphas staged once per block in LDS (16 KB);
// enc is read exactly once -> nontemporal loads
// ---------------------------------------------------------------------------
__global__ void k_context(const float* __restrict__ enc,
                          const float* __restrict__ alphas,
                          float* __restrict__ context) {
    __shared__ float4 s_al[P4];   // 16 KB
    const int b = blockIdx.y;
    const float4* a4 = (const float4*)(alphas + (size_t)b * HW);
    #pragma unroll
    for (int i = 0; i < 4; ++i)
        s_al[threadIdx.x + i * 256] = a4[threadIdx.x + i * 256];
    __syncthreads();

    const int wave = threadIdx.x >> 6;
    const int lane = threadIdx.x & 63;
    const int c = blockIdx.x * 4 + wave;
    const f4* e4 = (const f4*)(enc + ((size_t)b * EH + c) * HW);
    float acc = 0.f;
    #pragma unroll
    for (int it = 0; it < 16; ++it) {
        f4 v = __builtin_nontemporal_load(&e4[it * 64 + lane]);
        float4 al = s_al[it * 64 + lane];
        acc = fmaf(v.x, al.x, fmaf(v.y, al.y, fmaf(v.z, al.z, fmaf(v.w, al.w, acc))));
    }
    #pragma unroll
    for (int s = 32; s > 0; s >>= 1)
        acc += __shfl_down(acc, s);
    if (lane == 0) context[b * EH + c] = acc;
}

// ---------------------------------------------------------------------------
extern "C" void kernel_launch(void* const* d_in, const int* in_sizes, int n_in,
                              void* d_out, int out_size, void* d_ws, size_t ws_size,
                              hipStream_t stream) {
    const float* dec_h = (const float*)d_in[0];
    const float* weo   = (const float*)d_in[1];
    const float* enc   = (const float*)d_in[2];
    const float* W_dec = (const float*)d_in[3];
    const float* b_dec = (const float*)d_in[4];
    const float* w_en  = (const float*)d_in[5];
    const float* b_en  = (const float*)d_in[6];

    float* context = (float*)d_out;          // B*EH = 8192
    float* alphas  = context + B * EH;       // B*HW = 131072

    float* partial = (float*)d_ws;           // B*NCHUNK*HW = 1 M floats (4 MB)

    // k2 (fused dec_proj + scores): (pixel-chunks, a-chunks, batches) = (4, 8, 32)
    k_scores_part<<<dim3(P4 / 256, NCHUNK, B), 256, 0, stream>>>(
        weo, dec_h, W_dec, b_dec, w_en, partial);
    // k3: one block per batch
    k_softmax<<<dim3(B), 256, 0, stream>>>(partial, b_en, alphas);
    // k4: 64 channel-chunks x 32 batches, 4 waves/block = 4 channels/block
    k_context<<<dim3(EH / 4, B), 256, 0, stream>>>(enc, alphas, context);
}